// Round 1
// baseline (1674.584 us; speedup 1.0000x reference)
//
#include <hip/hip_runtime.h>
#include <stdint.h>
#include <stddef.h>

// ---------------------------------------------------------------------------
// MultiHeadAttentionLayer: B=2, S=4096, H=512, NH=8, HD=64
// out = concat( x [2,4096,512] fp32 , attention [2,8,4096,4096] fp32 )
//
// Pipeline:
//   gemm<0>: Q = query @ Wq^T + bq  -> Qbuf bf16 [b,h,s,d]
//   gemm<0>: K = key   @ Wk^T + bk  -> Kbuf bf16 [b,h,s,d]
//   gemm<1>: Vt = (value @ Wv^T + bv)^T -> Vtbuf bf16 [b,h,d,s]  (operand swap)
//   attn   : per (b,h,qtile=64): 2-pass max-free softmax; writes attention fp32
//            (1.07 GB, the structural HBM floor) and O -> Obuf fp32 [b,s,h*64+d]
//   gemm<2>: x = Obuf @ Wo^T + bo -> d_out fp32
// ---------------------------------------------------------------------------

typedef __attribute__((ext_vector_type(8))) short bf16x8;
typedef __attribute__((ext_vector_type(4))) float f32x4;

__device__ __forceinline__ unsigned short f2bf(float f) {
  unsigned u = __float_as_uint(f);
  u += 0x7fffu + ((u >> 16) & 1u);   // round-to-nearest-even
  return (unsigned short)(u >> 16);
}

__device__ __forceinline__ bf16x8 cvt8(const float* __restrict__ g) {
  const float4 x = ((const float4*)g)[0];
  const float4 y = ((const float4*)g)[1];
  bf16x8 r;
  r[0] = (short)f2bf(x.x); r[1] = (short)f2bf(x.y);
  r[2] = (short)f2bf(x.z); r[3] = (short)f2bf(x.w);
  r[4] = (short)f2bf(y.x); r[5] = (short)f2bf(y.y);
  r[6] = (short)f2bf(y.z); r[7] = (short)f2bf(y.w);
  return r;
}

// ---------------------------------------------------------------------------
// Tiled NT GEMM: C[m][n] = sum_k A[m][k]*Bm[n][k] (+bias), K=512 fixed.
// 128x128 tile, BK=32, 4 waves in 2x2, each wave 64x64 (4x4 mfma tiles).
// LDS rows = 4 segs of 16B; seg swizzle pos = seg ^ ((row>>1)&3) -> 2-way max.
// MODE 0: out bf16 head-split [b,h,s,d], bias per col n
// MODE 1: out bf16 Vt [(b*512+m)][s], n = b*4096+s, bias per row m
// MODE 2: out fp32 row-major [m*512+n], bias per col n
// ---------------------------------------------------------------------------
template <int MODE>
__global__ __launch_bounds__(256) void gemm_k(
    const float* __restrict__ A, const float* __restrict__ Bm,
    const float* __restrict__ bias, void* __restrict__ outp) {
  __shared__ __align__(16) unsigned short As[128 * 32];
  __shared__ __align__(16) unsigned short Bs[128 * 32];

  const int tid = threadIdx.x;
  const int w = tid >> 6, lane = tid & 63, qd = lane >> 4, ln = lane & 15;
  const int wm = w & 1, wn = w >> 1;
  const int m0 = blockIdx.y * 128, n0 = blockIdx.x * 128;

  f32x4 acc[4][4] = {};

  for (int k0 = 0; k0 < 512; k0 += 32) {
    __syncthreads();
#pragma unroll
    for (int i = 0; i < 2; i++) {
      const int sl = i * 256 + tid;
      const int row = sl >> 2, pos = sl & 3;
      const int seg = pos ^ ((row >> 1) & 3);
      *(bf16x8*)&As[sl * 8] = cvt8(A + (size_t)(m0 + row) * 512 + k0 + seg * 8);
      *(bf16x8*)&Bs[sl * 8] = cvt8(Bm + (size_t)(n0 + row) * 512 + k0 + seg * 8);
    }
    __syncthreads();

    bf16x8 af[4], bf[4];
#pragma unroll
    for (int mi = 0; mi < 4; mi++) {
      const int row = wm * 64 + mi * 16 + ln;
      const int pos = qd ^ ((row >> 1) & 3);
      af[mi] = *(const bf16x8*)&As[(row * 4 + pos) * 8];
    }
#pragma unroll
    for (int ni = 0; ni < 4; ni++) {
      const int row = wn * 64 + ni * 16 + ln;
      const int pos = qd ^ ((row >> 1) & 3);
      bf[ni] = *(const bf16x8*)&Bs[(row * 4 + pos) * 8];
    }
#pragma unroll
    for (int mi = 0; mi < 4; mi++)
#pragma unroll
      for (int ni = 0; ni < 4; ni++)
        acc[mi][ni] = __builtin_amdgcn_mfma_f32_16x16x32_bf16(
            af[mi], bf[ni], acc[mi][ni], 0, 0, 0);
  }

  // Epilogue. D layout: col = lane&15, row = (lane>>4)*4 + reg.
  if (MODE == 0) {
    unsigned short* out = (unsigned short*)outp;
#pragma unroll
    for (int ni = 0; ni < 4; ni++) {
      const int n = n0 + wn * 64 + ni * 16 + ln;
      const float bn = bias[n];
      const int h = n >> 6, d = n & 63;
#pragma unroll
      for (int mi = 0; mi < 4; mi++)
#pragma unroll
        for (int r = 0; r < 4; r++) {
          const int m = m0 + wm * 64 + mi * 16 + qd * 4 + r;
          const int b = m >> 12, s = m & 4095;
          out[(size_t)((b * 8 + h) * 4096 + s) * 64 + d] =
              f2bf(acc[mi][ni][r] + bn);
        }
    }
  } else if (MODE == 1) {
    unsigned short* out = (unsigned short*)outp;
#pragma unroll
    for (int mi = 0; mi < 4; mi++)
#pragma unroll
      for (int r = 0; r < 4; r++) {
        const int m = m0 + wm * 64 + mi * 16 + qd * 4 + r;
        const float bm = bias[m];
#pragma unroll
        for (int ni = 0; ni < 4; ni++) {
          const int n = n0 + wn * 64 + ni * 16 + ln;
          const int b = n >> 12, s = n & 4095;
          out[(size_t)(b * 512 + m) * 4096 + s] = f2bf(acc[mi][ni][r] + bm);
        }
      }
  } else {
    float* out = (float*)outp;
#pragma unroll
    for (int ni = 0; ni < 4; ni++) {
      const int n = n0 + wn * 64 + ni * 16 + ln;
      const float bn = bias[n];
#pragma unroll
      for (int mi = 0; mi < 4; mi++)
#pragma unroll
        for (int r = 0; r < 4; r++) {
          const int m = m0 + wm * 64 + mi * 16 + qd * 4 + r;
          out[(size_t)m * 512 + n] = acc[mi][ni][r] + bn;
        }
    }
  }
}

// ---------------------------------------------------------------------------
// Fused attention. Block = 256 thr (4 waves), Q-tile = 64 rows (16/wave),
// K-tile = 128. Pass 1: row sums of exp(QK^T/8) (max-free; |energy| << 88 so
// fp32 exp cannot overflow). Pass 2: recompute scores, write normalized probs
// to d_out, P->LDS roundtrip (D-layout -> A-operand layout), accumulate PV.
// LDS swizzles: rows of 8 segs use pos=seg^(row&7); 16 segs pos=seg^(row&15);
// Ps fp32 stride 68 -> all ds traffic <=2-way bank conflict (free, m136).
// ---------------------------------------------------------------------------
__global__ __launch_bounds__(256) void attn_k(
    const unsigned short* __restrict__ Qbuf,
    const unsigned short* __restrict__ Kbuf,
    const unsigned short* __restrict__ Vtbuf,
    float* __restrict__ attn_out, float* __restrict__ Obuf) {
  __shared__ __align__(16) unsigned short Qs[64 * 64];    //  8 KB
  __shared__ __align__(16) unsigned short Ks[128 * 64];   // 16 KB
  __shared__ __align__(16) unsigned short Vs[64 * 128];   // 16 KB (Vt: [d][kv])
  __shared__ __align__(16) float Ps[64 * 68];             // 17 KB

  const int tid = threadIdx.x;
  const int w = tid >> 6, lane = tid & 63, qd = lane >> 4, ln = lane & 15;
  const int qt = blockIdx.x, h = blockIdx.y, b = blockIdx.z;
  const int bh = b * 8 + h;

  const unsigned short* Qb = Qbuf + ((size_t)bh * 4096 + qt * 64) * 64;
  const unsigned short* Kb = Kbuf + (size_t)bh * 4096 * 64;
  const unsigned short* Vb = Vtbuf + (size_t)(b * 512 + h * 64) * 4096;
  float* attn = attn_out + ((size_t)bh * 4096 + qt * 64) * 4096;
  float* Ob = Obuf + (size_t)(b * 4096 + qt * 64) * 512 + h * 64;

  // stage Q tile once (64 rows x 8 segs)
#pragma unroll
  for (int i = 0; i < 2; i++) {
    const int sl = i * 256 + tid;
    const int row = sl >> 3, pos = sl & 7, seg = pos ^ (row & 7);
    *(bf16x8*)&Qs[sl * 8] = *(const bf16x8*)(Qb + (size_t)row * 64 + seg * 8);
  }
  __syncthreads();

  const float SCALE = 0.125f;  // 1/sqrt(64)
  const int qrow = w * 16 + ln;

  // Q fragments are kt-invariant: load once.
  bf16x8 a0, a1;
  {
    const int p0 = (qd) ^ (qrow & 7);
    const int p1 = (4 + qd) ^ (qrow & 7);
    a0 = *(const bf16x8*)&Qs[(qrow * 8 + p0) * 8];
    a1 = *(const bf16x8*)&Qs[(qrow * 8 + p1) * 8];
  }

  float l[4] = {0.f, 0.f, 0.f, 0.f};

  // ---------------- pass 1: denominators ----------------
  for (int kt = 0; kt < 32; kt++) {
    __syncthreads();
#pragma unroll
    for (int i = 0; i < 4; i++) {
      const int sl = i * 256 + tid;
      const int row = sl >> 3, pos = sl & 7, seg = pos ^ (row & 7);
      *(bf16x8*)&Ks[sl * 8] =
          *(const bf16x8*)(Kb + (size_t)(kt * 128 + row) * 64 + seg * 8);
    }
    __syncthreads();
#pragma unroll
    for (int c = 0; c < 8; c++) {
      const int krow = c * 16 + ln;
      const int p0 = qd ^ (krow & 7), p1 = (4 + qd) ^ (krow & 7);
      const bf16x8 b0 = *(const bf16x8*)&Ks[(krow * 8 + p0) * 8];
      const bf16x8 b1 = *(const bf16x8*)&Ks[(krow * 8 + p1) * 8];
      f32x4 s = {0.f, 0.f, 0.f, 0.f};
      s = __builtin_amdgcn_mfma_f32_16x16x32_bf16(a0, b0, s, 0, 0, 0);
      s = __builtin_amdgcn_mfma_f32_16x16x32_bf16(a1, b1, s, 0, 0, 0);
      l[0] += __expf(s[0] * SCALE);
      l[1] += __expf(s[1] * SCALE);
      l[2] += __expf(s[2] * SCALE);
      l[3] += __expf(s[3] * SCALE);
    }
  }
  // reduce across the 16 lanes (cols) of each quad
#pragma unroll
  for (int r = 0; r < 4; r++)
#pragma unroll
    for (int mask = 1; mask < 16; mask <<= 1)
      l[r] += __shfl_xor(l[r], mask, 64);
  const float rl[4] = {1.f / l[0], 1.f / l[1], 1.f / l[2], 1.f / l[3]};

  f32x4 o[4] = {};

  // ---------------- pass 2: probs out + PV ----------------
  for (int kt = 0; kt < 32; kt++) {
    __syncthreads();
#pragma unroll
    for (int i = 0; i < 4; i++) {
      const int sl = i * 256 + tid;
      {
        const int row = sl >> 3, pos = sl & 7, seg = pos ^ (row & 7);
        *(bf16x8*)&Ks[sl * 8] =
            *(const bf16x8*)(Kb + (size_t)(kt * 128 + row) * 64 + seg * 8);
      }
      {
        const int row = sl >> 4, pos = sl & 15, seg = pos ^ (row & 15);
        *(bf16x8*)&Vs[sl * 8] =
            *(const bf16x8*)(Vb + (size_t)row * 4096 + kt * 128 + seg * 8);
      }
    }
    __syncthreads();

    f32x4 sc[8];
#pragma unroll
    for (int c = 0; c < 8; c++) {
      const int krow = c * 16 + ln;
      const int p0 = qd ^ (krow & 7), p1 = (4 + qd) ^ (krow & 7);
      const bf16x8 b0 = *(const bf16x8*)&Ks[(krow * 8 + p0) * 8];
      const bf16x8 b1 = *(const bf16x8*)&Ks[(krow * 8 + p1) * 8];
      f32x4 s = {0.f, 0.f, 0.f, 0.f};
      s = __builtin_amdgcn_mfma_f32_16x16x32_bf16(a0, b0, s, 0, 0, 0);
      s = __builtin_amdgcn_mfma_f32_16x16x32_bf16(a1, b1, s, 0, 0, 0);
      sc[c] = s;
    }

#pragma unroll
    for (int half = 0; half < 2; half++) {
      const int qr = w * 16 + qd * 4;
#pragma unroll
      for (int c4 = 0; c4 < 4; c4++) {
        const int c = half * 4 + c4;
#pragma unroll
        for (int r = 0; r < 4; r++) {
          const float p = __expf(sc[c][r] * SCALE) * rl[r];
          attn[(size_t)(qr + r) * 4096 + kt * 128 + c * 16 + ln] = p;
          Ps[(qr + r) * 68 + c4 * 16 + ln] = p;  // per-wave rows: no barrier
        }
      }
#pragma unroll
      for (int ks2 = 0; ks2 < 2; ks2++) {
        const float* pr = &Ps[(w * 16 + ln) * 68 + ks2 * 32 + qd * 8];
        const float4 x = ((const float4*)pr)[0];
        const float4 y = ((const float4*)pr)[1];
        bf16x8 af;
        af[0] = (short)f2bf(x.x); af[1] = (short)f2bf(x.y);
        af[2] = (short)f2bf(x.z); af[3] = (short)f2bf(x.w);
        af[4] = (short)f2bf(y.x); af[5] = (short)f2bf(y.y);
        af[6] = (short)f2bf(y.z); af[7] = (short)f2bf(y.w);
        const int seg = (half * 2 + ks2) * 4 + qd;
#pragma unroll
        for (int cd = 0; cd < 4; cd++) {
          const int vrow = cd * 16 + ln;
          const int pos = seg ^ (vrow & 15);
          const bf16x8 bv = *(const bf16x8*)&Vs[(vrow * 16 + pos) * 8];
          o[cd] = __builtin_amdgcn_mfma_f32_16x16x32_bf16(af, bv, o[cd], 0, 0, 0);
        }
      }
    }
  }

  // write O (fp32) to Obuf
#pragma unroll
  for (int cd = 0; cd < 4; cd++)
#pragma unroll
    for (int r = 0; r < 4; r++)
      Ob[(size_t)(w * 16 + qd * 4 + r) * 512 + cd * 16 + ln] = o[cd][r];
}

// ---------------------------------------------------------------------------

extern "C" void kernel_launch(void* const* d_in, const int* in_sizes, int n_in,
                              void* d_out, int out_size, void* d_ws,
                              size_t ws_size, hipStream_t stream) {
  const float* query = (const float*)d_in[0];
  const float* key   = (const float*)d_in[1];
  const float* value = (const float*)d_in[2];
  const float* Wq = (const float*)d_in[3];
  const float* bq = (const float*)d_in[4];
  const float* Wk = (const float*)d_in[5];
  const float* bk = (const float*)d_in[6];
  const float* Wv = (const float*)d_in[7];
  const float* bv = (const float*)d_in[8];
  const float* Wo = (const float*)d_in[9];
  const float* bo = (const float*)d_in[10];

  const size_t NQK = (size_t)8192 * 512;  // elements per projection
  unsigned short* Qbuf = (unsigned short*)d_ws;
  unsigned short* Kbuf = Qbuf + NQK;
  unsigned short* Vtbuf = Kbuf + NQK;
  float* Obuf = (float*)(Vtbuf + NQK);

  float* xout = (float*)d_out;
  float* attn = xout + (size_t)2 * 4096 * 512;

  const dim3 blk(256);
  gemm_k<0><<<dim3(4, 64), blk, 0, stream>>>(query, Wq, bq, (void*)Qbuf);
  gemm_k<0><<<dim3(4, 64), blk, 0, stream>>>(key, Wk, bk, (void*)Kbuf);
  gemm_k<1><<<dim3(64, 4), blk, 0, stream>>>(Wv, value, bv, (void*)Vtbuf);
  attn_k<<<dim3(64, 8, 2), blk, 0, stream>>>(Qbuf, Kbuf, Vtbuf, attn, Obuf);
  gemm_k<2><<<dim3(4, 64), blk, 0, stream>>>(Obuf, Wo, bo, (void*)xout);
}